// Round 2
// 392.256 us; speedup vs baseline: 1.0204x; 1.0204x over previous
//
#include <hip/hip_runtime.h>

// ---------------------------------------------------------------------------
// STN pipeline, theta chain in FP64 (must match np float64 reference: sampler
// has floor() discontinuities at coord==223 with O(100..1000) jumps; f32
// noise upstream of theta flips floors -> fails. Any-order f64 lands ~1e-13
// from the np value -> flip set identical -> absmax stays ~73).
//
// R10 (resubmit after infra failure): conv1 weight path through the SCALAR
// pipe. Weight index ((ky*7+kx)*3+c)*8+oc is wave-uniform; reading
// pre-converted f64 weights from GLOBAL memory lets the compiler emit
// s_load + SGPR-operand v_fma_f64, removing ~588 ds_read_b128 (~24% of
// per-wave issue cycles) and the 9.4KB sw/sb LDS staging (47.1KB -> 36.8KB
// LDS -> better residency).
// k_wcvt pre-converts conv1 w+b to f64 in ws (~2us, serial before conv1).
// Also fixes latent pool1/pool2 overlap (pool1 is 6,083,072 doubles, pool2
// was placed at +6,081,152 -> 1920-double alias).
// ---------------------------------------------------------------------------

// Convert conv1 weights (1176) + bias (8) to f64 once per graph execution.
__global__ __launch_bounds__(256) void k_wcvt(
    const float* __restrict__ w1, const float* __restrict__ b1,
    double* __restrict__ wd) {
  int t = blockIdx.x * 256 + threadIdx.x;
  if (t < 1176) wd[t] = (double)w1[t];
  else if (t < 1184) wd[t] = (double)b1[t - 1176];
}

// conv1 + relu + maxpool : in (64,224,224,3) f32 -> out (64,109,109,8) f64
// Block: 4 pooled rows x 109 px (436 work items on 448 threads).
// Weights/bias come from global f64 (wd), read via scalar loads (uniform).
__global__ __launch_bounds__(448) void k_conv1(
    const float* __restrict__ in, const double* __restrict__ wd,
    double* __restrict__ out) {
  __shared__ float win[14 * 672];   // 14 input rows x 224*3

  // XCD swizzle: 28 tiles/batch, 8 batches/group (group pinned to one XCD).
  int g = blockIdx.x & 7;
  int i = blockIdx.x >> 3;          // 0..223
  int b = g * 8 + i / 28;
  int tile = i % 28;
  int py0 = 4 * tile;               // first pooled row (last tile: 108 only)
  int r0 = 8 * tile;                // first input row of the 14-row band

  // stage 14 input rows (row clamped to 223), full width, as float4
  {
    const float* ibb = in + (size_t)b * 150528;
    for (int idx = threadIdx.x; idx < 14 * 168; idx += 448) {
      int rr = idx / 168, c4 = idx % 168;
      int row = min(r0 + rr, 223);
      float4 v = reinterpret_cast<const float4*>(ibb + (size_t)row * 672)[c4];
      reinterpret_cast<float4*>(&win[rr * 672])[c4] = v;
    }
  }
  __syncthreads();

  int t = threadIdx.x;
  int py = py0 + t / 109;
  if (t < 436 && py < 109) {
    int px = t % 109;
    int lrb = 2 * (t / 109);        // 0,2,4,6

    double acc[2][2][8];
#pragma unroll
    for (int ii = 0; ii < 2; ++ii)
#pragma unroll
      for (int j = 0; j < 2; ++j)
#pragma unroll
        for (int k = 0; k < 8; ++k) acc[ii][j][k] = 0.0;

    for (int ky = 0; ky < 7; ++ky) {
      const float* r0p = &win[(lrb + ky) * 672 + 6 * px];
      const float* r1p = r0p + 672;
      float a0[24], a1[24];
#pragma unroll
      for (int j = 0; j < 12; ++j) {
        float2 u = reinterpret_cast<const float2*>(r0p)[j];
        a0[2 * j] = u.x; a0[2 * j + 1] = u.y;
        float2 v = reinterpret_cast<const float2*>(r1p)[j];
        a1[2 * j] = v.x; a1[2 * j + 1] = v.y;
      }
      const double* wk = wd + ky * 168;   // 7 kx * 3 c * 8 oc per ky
#pragma unroll
      for (int kx = 0; kx < 7; ++kx) {
#pragma unroll
        for (int c = 0; c < 3; ++c) {
          double v00 = (double)a0[kx * 3 + c];
          double v01 = (double)a0[kx * 3 + 3 + c];
          double v10 = (double)a1[kx * 3 + c];
          double v11 = (double)a1[kx * 3 + 3 + c];
          const double* wp = wk + (kx * 3 + c) * 8;   // wave-uniform -> s_load
#pragma unroll
          for (int oc = 0; oc < 8; ++oc) {
            double wv = wp[oc];
            acc[0][0][oc] = fma(v00, wv, acc[0][0][oc]);
            acc[0][1][oc] = fma(v01, wv, acc[0][1][oc]);
            acc[1][0][oc] = fma(v10, wv, acc[1][0][oc]);
            acc[1][1][oc] = fma(v11, wv, acc[1][1][oc]);
          }
        }
      }
    }

    double* op = out + ((size_t)b * 11881 + (size_t)py * 109 + px) * 8;
#pragma unroll
    for (int oc = 0; oc < 8; ++oc) {
      double m = fmax(fmax(acc[0][0][oc], acc[0][1][oc]),
                      fmax(acc[1][0][oc], acc[1][1][oc]));
      op[oc] = fmax(m + wd[1176 + oc], 0.0);
    }
  }
}

// conv2 + relu + maxpool : in (64,109,109,8) f64 -> out (64,52,52,10) f64
// Block: 4 pooled rows; items = 208 px x 2 oc-halves = 416 on 448 threads.
// Channel-planar band win2[cc][12][112]; two channel-half passes.
__global__ __launch_bounds__(448) void k_conv2(
    const double* __restrict__ in, const float* __restrict__ w,
    const float* __restrict__ bias, double* __restrict__ out) {
  __shared__ double win2[4 * 12 * 112];  // [cc][rr][x]
  __shared__ double sw[200 * 12];        // [tap(ky,kx,c)][oh*6+oc]
  __shared__ double sb[10];
  for (int i = threadIdx.x; i < 2000; i += 448) {
    int tap = i / 10, oc = i % 10;
    sw[tap * 12 + (oc / 5) * 6 + (oc % 5)] = (double)w[i];
  }
  if (threadIdx.x < 10) sb[threadIdx.x] = (double)bias[threadIdx.x];

  // XCD swizzle: 13 tiles/batch (52/4 exact), 8 batches/group.
  int g = blockIdx.x & 7;
  int i = blockIdx.x >> 3;          // 0..103
  int b = g * 8 + i / 13;
  int tile = i % 13;
  int py0 = 4 * tile;
  int r0 = 8 * tile;                // first conv2-input row; 12-row band,
                                    // max row = 8*12+11 = 107 <= 108 (no clamp)

  int t = threadIdx.x;
  bool valid = t < 416;
  int oh = t & 1;
  int p = t >> 1;                   // 0..207 within tile
  int px = p % 52;
  int lrb = 2 * (p / 52);           // 0,2,4,6

  double acc[2][2][5];
#pragma unroll
  for (int ii = 0; ii < 2; ++ii)
#pragma unroll
    for (int jj = 0; jj < 2; ++jj)
#pragma unroll
      for (int k = 0; k < 5; ++k) acc[ii][jj][k] = 0.0;

  const double* ib = in + (size_t)b * 11881 * 8;

  for (int h = 0; h < 2; ++h) {
    __syncthreads();  // protects win2 reuse + first-pass weight staging
    // stage 12 rows x 109 x channels [h*4..h*4+3] into planar layout
    for (int idx = threadIdx.x; idx < 12 * 109 * 2; idx += 448) {
      int d2 = idx & 1;               // channel pair (0-1 / 2-3)
      int x  = (idx >> 1) % 109;
      int rr = (idx >> 1) / 109;
      double2 v = *reinterpret_cast<const double2*>(
          ib + ((size_t)(r0 + rr) * 109 + x) * 8 + h * 4 + d2 * 2);
      win2[((d2 * 2) * 12 + rr) * 112 + x] = v.x;
      win2[((d2 * 2 + 1) * 12 + rr) * 112 + x] = v.y;
    }
    __syncthreads();

    if (valid) {
#pragma unroll
      for (int ky = 0; ky < 5; ++ky) {
        int rr0 = lrb + ky;
#pragma unroll
        for (int kx = 0; kx < 5; ++kx) {
          int xx = 2 * px + kx;
#pragma unroll
          for (int cc = 0; cc < 4; ++cc) {
            int c = h * 4 + cc;
            const double* pbase = &win2[(cc * 12 + rr0) * 112 + xx];
            double v00 = pbase[0];
            double v01 = pbase[1];
            double v10 = pbase[112];
            double v11 = pbase[113];
            const double* wp = &sw[((ky * 5 + kx) * 8 + c) * 12 + oh * 6];
#pragma unroll
            for (int oc = 0; oc < 5; ++oc) {
              double wv = wp[oc];
              acc[0][0][oc] = fma(v00, wv, acc[0][0][oc]);
              acc[0][1][oc] = fma(v01, wv, acc[0][1][oc]);
              acc[1][0][oc] = fma(v10, wv, acc[1][0][oc]);
              acc[1][1][oc] = fma(v11, wv, acc[1][1][oc]);
            }
          }
        }
      }
    }
  }

  if (valid) {
    int pix = py0 * 52 + p;           // p already row-major within tile
    double* op = out + ((size_t)b * 2704 + pix) * 10 + oh * 5;
#pragma unroll
    for (int oc = 0; oc < 5; ++oc) {
      double m = fmax(fmax(acc[0][0][oc], acc[0][1][oc]),
                      fmax(acc[1][0][oc], acc[1][1][oc]));
      op[oc] = fmax(m + sb[oh * 5 + oc], 0.0);
    }
  }
}

// fc1 partial dots: grid 1024 = (64 b) x (16 q); block 256 = 32 oc x 8 strips.
__global__ __launch_bounds__(256) void k_fc1(
    const double* __restrict__ xs, const float* __restrict__ w1,
    double* __restrict__ part) {
  int b = blockIdx.x >> 4;
  int q = blockIdx.x & 15;
  int oc = threadIdx.x & 31;
  int s = threadIdx.x >> 5;
  const double* xrow = xs + (size_t)b * 27040;

  int i0 = q * 1690 + s * 212;
  int i1 = min(i0 + 212, q * 1690 + 1690);
  double s0 = 0.0, s1 = 0.0;
  for (int i = i0; i + 1 < i1; i += 2) {
    s0 = fma(xrow[i],     (double)w1[(size_t)i * 32 + oc],       s0);
    s1 = fma(xrow[i + 1], (double)w1[(size_t)(i + 1) * 32 + oc], s1);
  }
  if ((i1 - i0) & 1)
    s0 = fma(xrow[i1 - 1], (double)w1[(size_t)(i1 - 1) * 32 + oc], s0);

  __shared__ double red[8][32];
  red[s][oc] = s0 + s1;
  __syncthreads();
  if (threadIdx.x < 32) {
    double v = 0.0;
#pragma unroll
    for (int k = 0; k < 8; ++k) v += red[k][threadIdx.x];
    part[((size_t)b * 16 + q) * 32 + threadIdx.x] = v;
  }
}

// fc1 reduce + ReLU + fc2 -> theta. 64 blocks x 64 threads.
__global__ __launch_bounds__(64) void k_fc2(
    const double* __restrict__ part, const float* __restrict__ b1,
    const float* __restrict__ w2, const float* __restrict__ b2,
    double* __restrict__ theta) {
  int b = blockIdx.x;
  __shared__ double h1[32];
  if (threadIdx.x < 32) {
    double v = (double)b1[threadIdx.x];
#pragma unroll
    for (int q = 0; q < 16; ++q)
      v += part[((size_t)b * 16 + q) * 32 + threadIdx.x];
    h1[threadIdx.x] = v > 0.0 ? v : 0.0;
  }
  __syncthreads();
  if (threadIdx.x < 6) {
    double v = (double)b2[threadIdx.x];
#pragma unroll
    for (int k = 0; k < 32; ++k) v += h1[k] * (double)w2[k * 6 + threadIdx.x];
    theta[b * 6 + threadIdx.x] = v;
  }
}

// affine grid + bilinear sampler, reference-exact (incl. extrapolation quirk).
__global__ __launch_bounds__(256) void k_sample(
    const float* __restrict__ img, const double* __restrict__ theta,
    float* __restrict__ out) {
  int idx = blockIdx.x * 256 + threadIdx.x;
  if (idx >= 64 * 224 * 224) return;
  int x = idx % 224;
  int t = idx / 224;
  int y = t % 224;
  int b = t / 224;

  const double* th = theta + b * 6;
  double t0 = th[0], t1 = th[1], t2 = th[2];
  double t3 = th[3], t4 = th[4], t5 = th[5];

  double xn = -1.0 + x * (2.0 / 223.0);
  double yn = -1.0 + y * (2.0 / 223.0);
  double xf = 0.5 * (t0 * xn + t1 * yn + t2 + 1.0) * 223.0;
  double yf = 0.5 * (t3 * xn + t4 * yn + t5 + 1.0) * 223.0;

  int x0 = (int)floor(xf);
  int y0 = (int)floor(yf);
  x0 = min(max(x0, 0), 223);
  y0 = min(max(y0, 0), 223);
  int x1 = min(x0 + 1, 223);
  int y1 = min(y0 + 1, 223);

  double x0f = (double)x0, x1f = (double)x1;
  double y0f = (double)y0, y1f = (double)y1;
  // weights from UNCLIPPED xf/yf — reference semantics (extrapolates)
  double wa = (x1f - xf) * (y1f - yf);
  double wb = (x1f - xf) * (yf - y0f);
  double wc = (xf - x0f) * (y1f - yf);
  double wd = (xf - x0f) * (yf - y0f);

  const float* p = img + (size_t)b * 150528;
  const float* Ia = p + ((size_t)y0 * 224 + x0) * 3;
  const float* Ib = p + ((size_t)y1 * 224 + x0) * 3;
  const float* Ic = p + ((size_t)y0 * 224 + x1) * 3;
  const float* Id = p + ((size_t)y1 * 224 + x1) * 3;

  float* op = out + (size_t)idx * 3;
#pragma unroll
  for (int c = 0; c < 3; ++c) {
    op[c] = (float)(wa * (double)Ia[c] + wb * (double)Ib[c] +
                    wc * (double)Ic[c] + wd * (double)Id[c]);
  }
}

extern "C" void kernel_launch(void* const* d_in, const int* in_sizes, int n_in,
                              void* d_out, int out_size, void* d_ws, size_t ws_size,
                              hipStream_t stream) {
  const float* inputs  = (const float*)d_in[0];  // (64,224,224,3)
  const float* conv1_w = (const float*)d_in[1];  // (7,7,3,8)
  const float* conv1_b = (const float*)d_in[2];  // (8)
  const float* conv2_w = (const float*)d_in[3];  // (5,5,8,10)
  const float* conv2_b = (const float*)d_in[4];  // (10)
  const float* fc1_w   = (const float*)d_in[5];  // (27040,32)
  const float* fc1_b   = (const float*)d_in[6];  // (32)
  const float* fc2_w   = (const float*)d_in[7];  // (32,6)
  const float* fc2_b   = (const float*)d_in[8];  // (6)
  float* outp = (float*)d_out;                   // (64,224,224,3)

  // ws layout (16B aligned): theta | fc partials | conv1 f64 weights | pools
  double* theta = (double*)d_ws;                            // 384 dbl
  double* part  = (double*)((char*)d_ws + 4096);            // 32768 dbl
  double* wd1   = (double*)((char*)d_ws + 4096 + 262144);   // 1184 dbl (9472B)
  double* pool1 = (double*)((char*)d_ws + 4096 + 262144 + 9472); // 6,083,072 d
  double* pool2 = pool1 + 6083072;                          // 1,730,560 d

  // Stage 0: f64 weight conversion for conv1 scalar-load path
  k_wcvt<<<5, 256, 0, stream>>>(conv1_w, conv1_b, wd1);
  // Stage 1: 28 tiles/batch * 64 batches (448-thread blocks), XCD-grouped
  k_conv1<<<28 * 64, 448, 0, stream>>>(inputs, wd1, pool1);
  // Stage 2: 13 tiles/batch * 64 batches (448-thread blocks), XCD-grouped
  k_conv2<<<13 * 64, 448, 0, stream>>>(pool1, conv2_w, conv2_b, pool2);
  // Stage 3
  k_fc1<<<1024, 256, 0, stream>>>(pool2, fc1_w, part);
  k_fc2<<<64, 64, 0, stream>>>(part, fc1_b, fc2_w, fc2_b, theta);
  // Stage 4
  k_sample<<<(64 * 224 * 224 + 255) / 256, 256, 0, stream>>>(inputs, theta, outp);
}